// Round 6
// baseline (717.578 us; speedup 1.0000x reference)
//
#include <hip/hip_runtime.h>
#include <hip/hip_bf16.h>

typedef __attribute__((ext_vector_type(8))) short bf16x8;
typedef __attribute__((ext_vector_type(4))) float f32x4;

#define MFMA __builtin_amdgcn_mfma_f32_16x16x32_bf16

__device__ __forceinline__ unsigned short f2bf(float f) {
    unsigned int u = __builtin_bit_cast(unsigned int, f);
    u += 0x7fffu + ((u >> 16) & 1u);
    return (unsigned short)(u >> 16);
}
__device__ __forceinline__ float bf2f(unsigned short h) {
    unsigned int u = ((unsigned int)h) << 16;
    return __builtin_bit_cast(float, u);
}

// ---------------------------------------------------------------------------
// Weight prep: W' [col][d] (bf16 hi/lo split), col-major-friendly for B-frags.
// ---------------------------------------------------------------------------
__global__ __launch_bounds__(256) void prep_w(const float* __restrict__ W,
                                              unsigned short* __restrict__ hi,
                                              unsigned short* __restrict__ lo,
                                              float scale, int hpd) {
    int tid = blockIdx.x * 256 + threadIdx.x;   // 512*512 total
    int col = tid >> 9, d = tid & 511;
    float x;
    if (hpd) x = W[(size_t)(col >> 6) * (512 * 64) + (size_t)d * 64 + (col & 63)];
    else     x = W[(size_t)d * 512 + col];
    x *= scale;
    unsigned short h = f2bf(x);
    hi[tid] = h;
    if (lo) lo[tid] = f2bf(x - bf2f(h));
}

// VT ones/zeros rows: rows 64..79 of each bh; row 64 = 1.0, rest 0.
__global__ __launch_bounds__(256) void vt_init(unsigned short* __restrict__ VT) {
    int tid = blockIdx.x * 256 + threadIdx.x;   // 32*16*2048
    int t = tid & 2047;
    int rr = (tid >> 11) & 15;
    int bh = tid >> 15;
    VT[((size_t)bh * 80 + 64 + rr) * 2048 + t] =
        (rr == 0) ? (unsigned short)0x3F80 : (unsigned short)0;
}

// ---------------------------------------------------------------------------
// Projection GEMM: Y[8192][512] = X[8192][512] * W'[512][512]
// Split 3-term when Wl != nullptr, else single-term.
// Grid 1024: 128 row-blocks (64 rows) x 8 col-blocks; wave owns 16 rows.
// mode 0: write hi/lo bf16 at [b*8+h][s][p]   (q, k)
// mode 1: write single bf16 TRANSPOSED at [(b*8+h)*80+p][t]  (v), packed x4
// ---------------------------------------------------------------------------
__global__ __launch_bounds__(256) void proj_kernel(
    const float* __restrict__ X,
    const unsigned short* __restrict__ Wh,
    const unsigned short* __restrict__ Wl,
    unsigned short* __restrict__ Oh,
    unsigned short* __restrict__ Ol,
    int mode)
{
    const int lane = threadIdx.x & 63;
    const int wave = threadIdx.x >> 6;
    const int lr = lane & 15, lg = lane >> 4;
    // XCD swizzle: 8 cb of 16 consecutive rb share an XCD's L2
    const int blk = blockIdx.x;
    const int xcd = blk & 7;
    const int loc = blk >> 3;             // 0..127
    const int rb = xcd * 16 + (loc >> 3); // 0..127
    const int cb = loc & 7;
    const int row0 = rb * 64 + wave * 16;
    const int col0 = cb * 64;

    f32x4 acc[4];
#pragma unroll
    for (int n = 0; n < 4; ++n) acc[n] = {0.f, 0.f, 0.f, 0.f};

    for (int ks = 0; ks < 16; ++ks) {
        const int d0 = ks * 32 + lg * 8;
        bf16x8 ah, al;
        {
            const float* px = X + (size_t)(row0 + lr) * 512 + d0;
            f32x4 x0 = *reinterpret_cast<const f32x4*>(px);
            f32x4 x1 = *reinterpret_cast<const f32x4*>(px + 4);
#pragma unroll
            for (int j = 0; j < 4; ++j) {
                unsigned short h0 = f2bf(x0[j]);
                unsigned short h1 = f2bf(x1[j]);
                ah[j]     = (short)h0;
                ah[j + 4] = (short)h1;
                al[j]     = (short)f2bf(x0[j] - bf2f(h0));
                al[j + 4] = (short)f2bf(x1[j] - bf2f(h1));
            }
        }
#pragma unroll
        for (int n = 0; n < 4; ++n) {
            size_t woff = (size_t)(col0 + n * 16 + lr) * 512 + d0;
            bf16x8 bh = *reinterpret_cast<const bf16x8*>(Wh + woff);
            f32x4 a = acc[n];
            a = MFMA(ah, bh, a, 0, 0, 0);
            if (Wl) {
                bf16x8 bl = *reinterpret_cast<const bf16x8*>(Wl + woff);
                a = MFMA(al, bh, a, 0, 0, 0);
                a = MFMA(ah, bl, a, 0, 0, 0);
            }
            acc[n] = a;
        }
    }

#pragma unroll
    for (int n = 0; n < 4; ++n) {
        int col = col0 + n * 16 + lr;
        int h = col >> 6, p = col & 63;
        if (mode == 0) {
#pragma unroll
            for (int r = 0; r < 4; ++r) {
                int grow = row0 + lg * 4 + r;
                int b = grow >> 11, s = grow & 2047;
                float v = acc[n][r];
                size_t o = ((size_t)(b * 8 + h) * 2048 + s) * 64 + p;
                unsigned short hv = f2bf(v);
                Oh[o] = hv;
                Ol[o] = f2bf(v - bf2f(hv));
            }
        } else {
            int grow0 = row0 + lg * 4;
            int b = grow0 >> 11, s0 = grow0 & 2047;
            ushort4 pk;
            pk.x = f2bf(acc[n][0]);
            pk.y = f2bf(acc[n][1]);
            pk.z = f2bf(acc[n][2]);
            pk.w = f2bf(acc[n][3]);
            *reinterpret_cast<ushort4*>(
                Oh + ((size_t)(b * 8 + h) * 80 + p) * 2048 + s0) = pk;
        }
    }
}

// ---------------------------------------------------------------------------
// Flash attention: 1024 blocks, one (b,h, 64-row q tile) each; 4 waves own
// 16 q rows apiece. Softmax denominator via ones-column PV accumulator.
// NOTE: plain __launch_bounds__(256) — the (256,4) variant forced VGPR=64 and
// serialized the load pipeline (R5: 390us, MfmaUtil 7.6%).
// ---------------------------------------------------------------------------
__global__ __launch_bounds__(256) void attn_kernel(
    const unsigned short* __restrict__ Qh, const unsigned short* __restrict__ Ql,
    const unsigned short* __restrict__ Kh, const unsigned short* __restrict__ Kl,
    const unsigned short* __restrict__ VT,   // [32][80][2048]
    unsigned short* __restrict__ Att)        // [4][2048][512]
{
    __shared__ __align__(16) unsigned char plds[4 * 16 * 144];
    const int lane = threadIdx.x & 63;
    const int wave = threadIdx.x >> 6;
    const int lr = lane & 15, lg = lane >> 4;
    // XCD swizzle: all 32 q-tiles of a bh (and 4 bh) per XCD -> K/V L2-resident
    const int blk = blockIdx.x;
    const int xcd = blk & 7;
    const int loc = blk >> 3;             // 0..127
    const int bh  = xcd * 4 + (loc >> 5); // 0..31
    const int qt  = loc & 31;
    const int q0 = qt * 64 + wave * 16;
    unsigned char* pl = plds + wave * (16 * 144);

    // Q fragments in registers (hi + lo), loaded once
    bf16x8 qfh[2], qfl[2];
#pragma unroll
    for (int ks = 0; ks < 2; ++ks) {
        size_t off = ((size_t)bh * 2048 + q0 + lr) * 64 + ks * 32 + lg * 8;
        qfh[ks] = *reinterpret_cast<const bf16x8*>(Qh + off);
        qfl[ks] = *reinterpret_cast<const bf16x8*>(Ql + off);
    }

    f32x4 oacc[5];   // [0..3] = output cols, [4] = softmax denominator (ones col)
    f32x4 mrun;
#pragma unroll
    for (int n = 0; n < 5; ++n) oacc[n] = {0.f, 0.f, 0.f, 0.f};
    mrun = {-1e30f, -1e30f, -1e30f, -1e30f};

    const float LOG2E = 1.4426950408889634f;

    for (int kt = 0; kt < 32; ++kt) {
        // ---- scores: S = (Q/8) K^T, split 3-term ----
        f32x4 sc[4];
#pragma unroll
        for (int n = 0; n < 4; ++n) {
            size_t koff = ((size_t)bh * 2048 + kt * 64 + n * 16 + lr) * 64 + lg * 8;
            bf16x8 kh0 = *reinterpret_cast<const bf16x8*>(Kh + koff);
            bf16x8 kh1 = *reinterpret_cast<const bf16x8*>(Kh + koff + 32);
            bf16x8 kl0 = *reinterpret_cast<const bf16x8*>(Kl + koff);
            bf16x8 kl1 = *reinterpret_cast<const bf16x8*>(Kl + koff + 32);
            f32x4 a = {0.f, 0.f, 0.f, 0.f};
            a = MFMA(qfh[0], kh0, a, 0, 0, 0);
            a = MFMA(qfh[1], kh1, a, 0, 0, 0);
            a = MFMA(qfl[0], kh0, a, 0, 0, 0);
            a = MFMA(qfl[1], kh1, a, 0, 0, 0);
            a = MFMA(qfh[0], kl0, a, 0, 0, 0);
            a = MFMA(qfh[1], kl1, a, 0, 0, 0);
            sc[n] = a;
        }

        // ---- row max (rows on (lg,r), cols across 16 lr lanes) ----
        f32x4 tmax;
#pragma unroll
        for (int r = 0; r < 4; ++r)
            tmax[r] = fmaxf(fmaxf(sc[0][r], sc[1][r]), fmaxf(sc[2][r], sc[3][r]));
#pragma unroll
        for (int msk = 1; msk < 16; msk <<= 1)
#pragma unroll
            for (int r = 0; r < 4; ++r)
                tmax[r] = fmaxf(tmax[r], __shfl_xor(tmax[r], msk));

        // ---- defer-max: only rescale when a row max grew by > 8 ----
        int need = 0;
#pragma unroll
        for (int r = 0; r < 4; ++r) need |= (tmax[r] > mrun[r] + 8.0f) ? 1 : 0;
        if (__any(need)) {
            f32x4 scale;
#pragma unroll
            for (int r = 0; r < 4; ++r) {
                float mnew = fmaxf(mrun[r], tmax[r]);
                scale[r] = exp2f((mrun[r] - mnew) * LOG2E);
                mrun[r] = mnew;
            }
#pragma unroll
            for (int n = 0; n < 5; ++n)
#pragma unroll
                for (int r = 0; r < 4; ++r) oacc[n][r] *= scale[r];
        }

        // ---- P = exp(S - m), store to per-wave LDS (swizzled) ----
        f32x4 mb;
#pragma unroll
        for (int r = 0; r < 4; ++r) mb[r] = mrun[r] * LOG2E;
#pragma unroll
        for (int n = 0; n < 4; ++n)
#pragma unroll
            for (int r = 0; r < 4; ++r) {
                float p = exp2f(sc[n][r] * LOG2E - mb[r]);
                int s = lg * 4 + r;
                int t = n * 16 + lr;
                int addr = s * 144 + ((2 * t) ^ ((s & 7) << 4));
                *reinterpret_cast<unsigned short*>(pl + addr) = f2bf(p);
            }

        // ---- P A-frags from LDS ----
        bf16x8 pa[2];
#pragma unroll
        for (int ks = 0; ks < 2; ++ks) {
            int s = lr;
            int t0 = ks * 32 + lg * 8;
            int addr = s * 144 + ((2 * t0) ^ ((s & 7) << 4));
            pa[ks] = *reinterpret_cast<const bf16x8*>(pl + addr);
        }

        // ---- PV (n=4 is the ones column -> denominator) ----
#pragma unroll
        for (int n = 0; n < 5; ++n) {
            size_t voff = ((size_t)bh * 80 + n * 16 + lr) * 2048 + kt * 64 + lg * 8;
            bf16x8 vb0 = *reinterpret_cast<const bf16x8*>(VT + voff);
            bf16x8 vb1 = *reinterpret_cast<const bf16x8*>(VT + voff + 32);
            f32x4 a = oacc[n];
            a = MFMA(pa[0], vb0, a, 0, 0, 0);
            a = MFMA(pa[1], vb1, a, 0, 0, 0);
            oacc[n] = a;
        }
    }

    // ---- epilogue: denominator lives in lane lr==0 of each lg group ----
    const int b = bh >> 3, h = bh & 7;
    f32x4 inv;
#pragma unroll
    for (int r = 0; r < 4; ++r) {
        float denom = __shfl(oacc[4][r], (lane & 48));
        inv[r] = 1.0f / denom;
    }
#pragma unroll
    for (int n = 0; n < 4; ++n)
#pragma unroll
        for (int r = 0; r < 4; ++r) {
            int s = q0 + lg * 4 + r;
            int p = n * 16 + lr;
            Att[((size_t)b * 2048 + s) * 512 + h * 64 + p] =
                f2bf(oacc[n][r] * inv[r]);
        }
}

// ---------------------------------------------------------------------------
// Output projection: Out[8192][512] = Att[8192][512] * Wo  (single bf16)
// Grid 1024: 128 row-blocks (64 rows) x 8 col-blocks; wave owns 16 rows.
// ---------------------------------------------------------------------------
__global__ __launch_bounds__(256) void outproj_kernel(
    const unsigned short* __restrict__ A,
    const unsigned short* __restrict__ WT,   // [512 col][512 k]
    float* __restrict__ Out)
{
    const int lane = threadIdx.x & 63;
    const int wave = threadIdx.x >> 6;
    const int lr = lane & 15, lg = lane >> 4;
    const int blk = blockIdx.x;
    const int xcd = blk & 7;
    const int loc = blk >> 3;
    const int rb = xcd * 16 + (loc >> 3);
    const int cb = loc & 7;
    const int row0 = rb * 64 + wave * 16;
    const int col0 = cb * 64;

    f32x4 acc[4];
#pragma unroll
    for (int n = 0; n < 4; ++n) acc[n] = {0.f, 0.f, 0.f, 0.f};

    for (int ks = 0; ks < 16; ++ks) {
        const int k0 = ks * 32 + lg * 8;
        bf16x8 af = *reinterpret_cast<const bf16x8*>(
            A + (size_t)(row0 + lr) * 512 + k0);
#pragma unroll
        for (int n = 0; n < 4; ++n) {
            bf16x8 bf = *reinterpret_cast<const bf16x8*>(
                WT + (size_t)(col0 + n * 16 + lr) * 512 + k0);
            acc[n] = MFMA(af, bf, acc[n], 0, 0, 0);
        }
    }

#pragma unroll
    for (int n = 0; n < 4; ++n)
#pragma unroll
        for (int r = 0; r < 4; ++r)
            Out[(size_t)(row0 + lg * 4 + r) * 512 + col0 + n * 16 + lr] =
                acc[n][r];
}

// ---------------------------------------------------------------------------
extern "C" void kernel_launch(void* const* d_in, const int* in_sizes, int n_in,
                              void* d_out, int out_size, void* d_ws, size_t ws_size,
                              hipStream_t stream) {
    (void)in_sizes; (void)n_in; (void)out_size; (void)ws_size;
    const float* q  = (const float*)d_in[0];
    const float* k  = (const float*)d_in[1];
    const float* v  = (const float*)d_in[2];
    const float* Wq = (const float*)d_in[3];
    const float* Wk = (const float*)d_in[4];
    const float* Wv = (const float*)d_in[5];
    const float* Wo = (const float*)d_in[6];
    float* out = (float*)d_out;

    size_t off = 0;
    auto take = [&](size_t bytes) -> void* {
        void* p = (char*)d_ws + off;
        off += (bytes + 255) & ~(size_t)255;
        return p;
    };
    const size_t WSZ  = 512 * 512 * sizeof(unsigned short);              // 512 KB
    const size_t BSZ  = (size_t)32 * 2048 * 64 * sizeof(unsigned short); // 8 MB
    const size_t VTSZ = (size_t)32 * 80 * 2048 * sizeof(unsigned short); // 10 MB

    unsigned short* WqTh = (unsigned short*)take(WSZ);
    unsigned short* WqTl = (unsigned short*)take(WSZ);
    unsigned short* WkTh = (unsigned short*)take(WSZ);
    unsigned short* WkTl = (unsigned short*)take(WSZ);
    unsigned short* WvTh = (unsigned short*)take(WSZ);
    unsigned short* WoT  = (unsigned short*)take(WSZ);
    unsigned short* Qh   = (unsigned short*)take(BSZ);
    unsigned short* Ql   = (unsigned short*)take(BSZ);
    unsigned short* Kh   = (unsigned short*)take(BSZ);
    unsigned short* Kl   = (unsigned short*)take(BSZ);
    unsigned short* VT   = (unsigned short*)take(VTSZ);
    unsigned short* Att  = (unsigned short*)take(BSZ);

    // weight prep (1/sqrt(P)=0.125 folded into Wq); Wv single bf16 (no lo)
    prep_w<<<1024, 256, 0, stream>>>(Wq, WqTh, WqTl, 0.125f, 1);
    prep_w<<<1024, 256, 0, stream>>>(Wk, WkTh, WkTl, 1.0f, 1);
    prep_w<<<1024, 256, 0, stream>>>(Wv, WvTh, nullptr, 1.0f, 1);
    prep_w<<<1024, 256, 0, stream>>>(Wo, WoT, nullptr, 1.0f, 0);
    vt_init<<<4096, 256, 0, stream>>>(VT);

    // projections (q,k: split 3-term; v: single-term)
    proj_kernel<<<1024, 256, 0, stream>>>(q, WqTh, WqTl, Qh, Ql, 0);
    proj_kernel<<<1024, 256, 0, stream>>>(k, WkTh, WkTl, Kh, Kl, 0);
    proj_kernel<<<1024, 256, 0, stream>>>(v, WvTh, nullptr, VT, nullptr, 1);

    // flash attention
    attn_kernel<<<1024, 256, 0, stream>>>(Qh, Ql, Kh, Kl, VT, Att);

    // output projection
    outproj_kernel<<<1024, 256, 0, stream>>>(Att, WoT, out);
}

// Round 10
// 442.379 us; speedup vs baseline: 1.6221x; 1.6221x over previous
//
#include <hip/hip_runtime.h>
#include <hip/hip_bf16.h>

typedef __attribute__((ext_vector_type(8))) short bf16x8;
typedef __attribute__((ext_vector_type(4))) float f32x4;

#define MFMA __builtin_amdgcn_mfma_f32_16x16x32_bf16

__device__ __forceinline__ unsigned short f2bf(float f) {
    unsigned int u = __builtin_bit_cast(unsigned int, f);
    u += 0x7fffu + ((u >> 16) & 1u);
    return (unsigned short)(u >> 16);
}
__device__ __forceinline__ float bf2f(unsigned short h) {
    unsigned int u = ((unsigned int)h) << 16;
    return __builtin_bit_cast(float, u);
}

// async global->LDS, 16B per lane. LDS dest is wave-uniform base + lane*16.
__device__ __forceinline__ void gld16(const void* g, void* l) {
    __builtin_amdgcn_global_load_lds(
        (const __attribute__((address_space(1))) void*)g,
        (__attribute__((address_space(3))) void*)(unsigned long long)l,
        16, 0, 0);
}

// ---------------------------------------------------------------------------
// Weight prep: W' [col][d] (bf16 hi/lo split), col-major-friendly for B-frags.
// ---------------------------------------------------------------------------
__global__ __launch_bounds__(256) void prep_w(const float* __restrict__ W,
                                              unsigned short* __restrict__ hi,
                                              unsigned short* __restrict__ lo,
                                              float scale, int hpd) {
    int tid = blockIdx.x * 256 + threadIdx.x;   // 512*512 total
    int col = tid >> 9, d = tid & 511;
    float x;
    if (hpd) x = W[(size_t)(col >> 6) * (512 * 64) + (size_t)d * 64 + (col & 63)];
    else     x = W[(size_t)d * 512 + col];
    x *= scale;
    unsigned short h = f2bf(x);
    hi[tid] = h;
    if (lo) lo[tid] = f2bf(x - bf2f(h));
}

// VT ones/zeros rows: rows 64..79 of each bh (stride 96); row 64 = 1.0, rest 0.
__global__ __launch_bounds__(256) void vt_init(unsigned short* __restrict__ VT) {
    int tid = blockIdx.x * 256 + threadIdx.x;   // 32*16*2048
    int t = tid & 2047;
    int rr = (tid >> 11) & 15;
    int bh = tid >> 15;
    VT[((size_t)bh * 96 + 64 + rr) * 2048 + t] =
        (rr == 0) ? (unsigned short)0x3F80 : (unsigned short)0;
}

// ---------------------------------------------------------------------------
// Projection GEMM: Y[8192][512] = X[8192][512] * W'[512][512]
// Split 3-term when Wl != nullptr, else single-term.
// mode 0: write hi/lo bf16 at [b*8+h][s][p]   (q, k)
// mode 1: write single bf16 TRANSPOSED at [(b*8+h)*96+p][t]  (v), packed x4
// ---------------------------------------------------------------------------
__global__ __launch_bounds__(256) void proj_kernel(
    const float* __restrict__ X,
    const unsigned short* __restrict__ Wh,
    const unsigned short* __restrict__ Wl,
    unsigned short* __restrict__ Oh,
    unsigned short* __restrict__ Ol,
    int mode)
{
    const int lane = threadIdx.x & 63;
    const int wave = threadIdx.x >> 6;
    const int lr = lane & 15, lg = lane >> 4;
    const int blk = blockIdx.x;
    const int xcd = blk & 7;
    const int loc = blk >> 3;             // 0..127
    const int rb = xcd * 16 + (loc >> 3); // 0..127
    const int cb = loc & 7;
    const int row0 = rb * 64 + wave * 16;
    const int col0 = cb * 64;

    f32x4 acc[4];
#pragma unroll
    for (int n = 0; n < 4; ++n) acc[n] = {0.f, 0.f, 0.f, 0.f};

    for (int ks = 0; ks < 16; ++ks) {
        const int d0 = ks * 32 + lg * 8;
        bf16x8 ah, al;
        {
            const float* px = X + (size_t)(row0 + lr) * 512 + d0;
            f32x4 x0 = *reinterpret_cast<const f32x4*>(px);
            f32x4 x1 = *reinterpret_cast<const f32x4*>(px + 4);
#pragma unroll
            for (int j = 0; j < 4; ++j) {
                unsigned short h0 = f2bf(x0[j]);
                unsigned short h1 = f2bf(x1[j]);
                ah[j]     = (short)h0;
                ah[j + 4] = (short)h1;
                al[j]     = (short)f2bf(x0[j] - bf2f(h0));
                al[j + 4] = (short)f2bf(x1[j] - bf2f(h1));
            }
        }
#pragma unroll
        for (int n = 0; n < 4; ++n) {
            size_t woff = (size_t)(col0 + n * 16 + lr) * 512 + d0;
            bf16x8 bh = *reinterpret_cast<const bf16x8*>(Wh + woff);
            f32x4 a = acc[n];
            a = MFMA(ah, bh, a, 0, 0, 0);
            if (Wl) {
                bf16x8 bl = *reinterpret_cast<const bf16x8*>(Wl + woff);
                a = MFMA(al, bh, a, 0, 0, 0);
                a = MFMA(ah, bl, a, 0, 0, 0);
            }
            acc[n] = a;
        }
    }

#pragma unroll
    for (int n = 0; n < 4; ++n) {
        int col = col0 + n * 16 + lr;
        int h = col >> 6, p = col & 63;
        if (mode == 0) {
#pragma unroll
            for (int r = 0; r < 4; ++r) {
                int grow = row0 + lg * 4 + r;
                int b = grow >> 11, s = grow & 2047;
                float v = acc[n][r];
                size_t o = ((size_t)(b * 8 + h) * 2048 + s) * 64 + p;
                unsigned short hv = f2bf(v);
                Oh[o] = hv;
                Ol[o] = f2bf(v - bf2f(hv));
            }
        } else {
            int grow0 = row0 + lg * 4;
            int b = grow0 >> 11, s0 = grow0 & 2047;
            ushort4 pk;
            pk.x = f2bf(acc[n][0]);
            pk.y = f2bf(acc[n][1]);
            pk.z = f2bf(acc[n][2]);
            pk.w = f2bf(acc[n][3]);
            *reinterpret_cast<ushort4*>(
                Oh + ((size_t)(b * 8 + h) * 96 + p) * 2048 + s0) = pk;
        }
    }
}

// ---------------------------------------------------------------------------
// Flash attention v3: 512 blocks = (bh, 128-row q tile); 4 waves x 32 rows.
// K/V double-buffered in LDS via async global_load_lds (counted vmcnt(7)).
// Pre-swizzled staging sources; XOR-swizzled ds_read_b128 frag reads.
// Swapped QK^T (S^T = mfma(K,Q)) -> in-lane row-max + b64 P stores.
// Softmax denominator via ones-column of VT (rows 64..79).
// ---------------------------------------------------------------------------
__global__ __launch_bounds__(256) void attn_kernel(
    const unsigned short* __restrict__ Qh, const unsigned short* __restrict__ Ql,
    const unsigned short* __restrict__ Kh, const unsigned short* __restrict__ Kl,
    const unsigned short* __restrict__ VT,   // [32][96][2048]
    unsigned short* __restrict__ Att)        // [4][2048][512]
{
    __shared__ __align__(16) unsigned char sK[2][16384];  // hi 8K + lo 8K, [64][64] each
    __shared__ __align__(16) unsigned char sV[2][12288];  // [96][64]
    __shared__ __align__(16) unsigned char sP[4][4736];   // per-wave: 32x144 P + 32 f32 scale

    const int lane = threadIdx.x & 63;
    const int w    = threadIdx.x >> 6;
    const int lr = lane & 15, lg = lane >> 4;

    const int blk = blockIdx.x;
    const int xcd = blk & 7;
    const int loc = blk >> 3;             // 0..63
    const int bh  = xcd * 4 + (loc >> 4); // 0..31
    const int qt  = loc & 15;
    const int q0  = qt * 128 + w * 32;

    unsigned char* spw = sP[w];

    // ---- Q fragments (hi + lo), 2 m-blocks x 2 k-slices, loaded once ----
    bf16x8 qfh[2][2], qfl[2][2];
#pragma unroll
    for (int m = 0; m < 2; ++m)
#pragma unroll
        for (int ks = 0; ks < 2; ++ks) {
            size_t off = ((size_t)bh * 2048 + q0 + m * 16 + lr) * 64 + ks * 32 + lg * 8;
            qfh[m][ks] = *reinterpret_cast<const bf16x8*>(Qh + off);
            qfl[m][ks] = *reinterpret_cast<const bf16x8*>(Ql + off);
        }

    // ---- per-lane pre-swizzled staging source pointers ----
    // lane covers (row = base + lane/8, col16 = (lane%8) ^ ((lane/8)&7))
    const int rb8 = lane >> 3;
    const int c16 = (lane & 7) ^ (rb8 & 7);
    const unsigned short* khp = Kh + ((size_t)bh * 2048 + w * 16 + rb8) * 64 + c16 * 8;
    const unsigned short* klp = Kl + ((size_t)bh * 2048 + w * 16 + rb8) * 64 + c16 * 8;
    const unsigned short* vp  = VT + ((size_t)bh * 96 + w * 24 + rb8) * 2048 + c16 * 8;

    // ---- LDS frag read offsets (XOR-unswizzle) ----
    const int x0 = ((lg ^ (lr & 7)) << 4);
    const int koff0 = lr * 128 + x0;
    const int koff1 = lr * 128 + (x0 ^ 64);

    // ---- prologue: stage kt=0 into buffer 0 ----
    {
        unsigned char* kb = sK[0]; unsigned char* vb = sV[0];
        gld16(khp,        kb + w * 2048);
        gld16(khp + 512,  kb + w * 2048 + 1024);
        gld16(klp,        kb + 8192 + w * 2048);
        gld16(klp + 512,  kb + 8192 + w * 2048 + 1024);
        gld16(vp,         vb + w * 3072);
        gld16(vp + 16384, vb + w * 3072 + 1024);
        gld16(vp + 32768, vb + w * 3072 + 2048);
        khp += 4096; klp += 4096; vp += 64;
    }

    f32x4 oacc[2][5];   // [m][0..3]=output cols, [m][4]=denominator (ones col)
    float mrun[2];
#pragma unroll
    for (int m = 0; m < 2; ++m) {
        mrun[m] = -1e30f;
#pragma unroll
        for (int n = 0; n < 5; ++n) oacc[m][n] = {0.f, 0.f, 0.f, 0.f};
    }

    const float LOG2E = 1.4426950408889634f;

    for (int kt = 0; kt < 32; ++kt) {
        const int cur = kt & 1;
        if (kt < 31) {
            unsigned char* kb = sK[cur ^ 1]; unsigned char* vb = sV[cur ^ 1];
            gld16(khp,        kb + w * 2048);
            gld16(khp + 512,  kb + w * 2048 + 1024);
            gld16(klp,        kb + 8192 + w * 2048);
            gld16(klp + 512,  kb + 8192 + w * 2048 + 1024);
            gld16(vp,         vb + w * 3072);
            gld16(vp + 16384, vb + w * 3072 + 1024);
            gld16(vp + 32768, vb + w * 3072 + 2048);
            khp += 4096; klp += 4096; vp += 64;
            asm volatile("s_waitcnt vmcnt(7)" ::: "memory");  // cur buf staged; next in flight
        } else {
            asm volatile("s_waitcnt vmcnt(0)" ::: "memory");
        }
        __builtin_amdgcn_sched_barrier(0);
        __builtin_amdgcn_s_barrier();

        unsigned char* kb = sK[cur];
        unsigned char* vbuf = sV[cur];

        // ---- scores S^T[t][s] = mfma(K, Q), split 3-term ----
        f32x4 sc[2][4];
#pragma unroll
        for (int n = 0; n < 4; ++n) {
            bf16x8 kh0 = *reinterpret_cast<const bf16x8*>(kb + n * 2048 + koff0);
            bf16x8 kh1 = *reinterpret_cast<const bf16x8*>(kb + n * 2048 + koff1);
            bf16x8 kl0 = *reinterpret_cast<const bf16x8*>(kb + 8192 + n * 2048 + koff0);
            bf16x8 kl1 = *reinterpret_cast<const bf16x8*>(kb + 8192 + n * 2048 + koff1);
#pragma unroll
            for (int m = 0; m < 2; ++m) {
                f32x4 a = {0.f, 0.f, 0.f, 0.f};
                a = MFMA(kh0, qfh[m][0], a, 0, 0, 0);
                a = MFMA(kh1, qfh[m][1], a, 0, 0, 0);
                a = MFMA(kh0, qfl[m][0], a, 0, 0, 0);
                a = MFMA(kh1, qfl[m][1], a, 0, 0, 0);
                a = MFMA(kl0, qfh[m][0], a, 0, 0, 0);
                a = MFMA(kl1, qfh[m][1], a, 0, 0, 0);
                sc[m][n] = a;   // lane: s = m*16+lr, t = n*16+lg*4+r
            }
        }

        // ---- row max over t: in-lane 16, then lg-group reduce (xor16, xor32) ----
        float tmax[2];
#pragma unroll
        for (int m = 0; m < 2; ++m) {
            float tm = fmaxf(fmaxf(sc[m][0][0], sc[m][0][1]),
                             fmaxf(sc[m][0][2], sc[m][0][3]));
            tm = fmaxf(tm, fmaxf(fmaxf(sc[m][1][0], sc[m][1][1]),
                                 fmaxf(sc[m][1][2], sc[m][1][3])));
            tm = fmaxf(tm, fmaxf(fmaxf(sc[m][2][0], sc[m][2][1]),
                                 fmaxf(sc[m][2][2], sc[m][2][3])));
            tm = fmaxf(tm, fmaxf(fmaxf(sc[m][3][0], sc[m][3][1]),
                                 fmaxf(sc[m][3][2], sc[m][3][3])));
            tm = fmaxf(tm, __shfl_xor(tm, 16));
            tm = fmaxf(tm, __shfl_xor(tm, 32));
            tmax[m] = tm;
        }

        // ---- defer-max rescale (rare); scale broadcast via LDS ----
        int need = (tmax[0] > mrun[0] + 8.0f) || (tmax[1] > mrun[1] + 8.0f);
        if (__any(need)) {
#pragma unroll
            for (int m = 0; m < 2; ++m) {
                float mnew = fmaxf(mrun[m], tmax[m]);
                float scl = exp2f((mrun[m] - mnew) * LOG2E);
                *reinterpret_cast<float*>(spw + 4608 + (m * 16 + lr) * 4) = scl;
                mrun[m] = mnew;
            }
#pragma unroll
            for (int m = 0; m < 2; ++m) {
                f32x4 s4 = *reinterpret_cast<const f32x4*>(
                    spw + 4608 + (m * 16 + lg * 4) * 4);
#pragma unroll
                for (int n = 0; n < 5; ++n)
#pragma unroll
                    for (int r = 0; r < 4; ++r) oacc[m][n][r] *= s4[r];
            }
        }

        // ---- P = exp2(sc*log2e - m), cvt_pk pack, b64 stores (4 t-contig) ----
#pragma unroll
        for (int m = 0; m < 2; ++m) {
            float mb = mrun[m] * LOG2E;
            int s = m * 16 + lr;
            int swz = (s & 7) << 4;
#pragma unroll
            for (int n = 0; n < 4; ++n) {
                float e0 = exp2f(sc[m][n][0] * LOG2E - mb);
                float e1 = exp2f(sc[m][n][1] * LOG2E - mb);
                float e2 = exp2f(sc[m][n][2] * LOG2E - mb);
                float e3 = exp2f(sc[m][n][3] * LOG2E - mb);
                unsigned int u01, u23;
                asm("v_cvt_pk_bf16_f32 %0, %1, %2" : "=v"(u01) : "v"(e0), "v"(e1));
                asm("v_cvt_pk_bf16_f32 %0, %1, %2" : "=v"(u23) : "v"(e2), "v"(e3));
                uint2 pk; pk.x = u01; pk.y = u23;
                int t2 = (n * 16 + lg * 4) * 2;
                *reinterpret_cast<uint2*>(spw + s * 144 + (t2 ^ swz)) = pk;
            }
        }

        // ---- P A-frags from LDS ----
        bf16x8 pa[2][2];
#pragma unroll
        for (int m = 0; m < 2; ++m) {
            int s = m * 16 + lr;
            int swz = (s & 7) << 4;
#pragma unroll
            for (int ks = 0; ks < 2; ++ks) {
                int t2 = (ks * 32 + lg * 8) * 2;
                pa[m][ks] = *reinterpret_cast<const bf16x8*>(
                    spw + s * 144 + (t2 ^ swz));
            }
        }

        // ---- PV from staged V (n=4 is ones column -> denominator) ----
#pragma unroll
        for (int n = 0; n < 5; ++n) {
            bf16x8 vb0 = *reinterpret_cast<const bf16x8*>(vbuf + n * 2048 + koff0);
            bf16x8 vb1 = *reinterpret_cast<const bf16x8*>(vbuf + n * 2048 + koff1);
#pragma unroll
            for (int m = 0; m < 2; ++m) {
                f32x4 a = oacc[m][n];
                a = MFMA(pa[m][0], vb0, a, 0, 0, 0);
                a = MFMA(pa[m][1], vb1, a, 0, 0, 0);
                oacc[m][n] = a;
            }
        }

        __builtin_amdgcn_s_barrier();   // all waves done reading buf[cur]
    }

    // ---- epilogue: denominator at col lr==0 of oacc[m][4]; broadcast in lg group
    const int b = bh >> 3, h = bh & 7;
#pragma unroll
    for (int m = 0; m < 2; ++m) {
        f32x4 inv;
#pragma unroll
        for (int r = 0; r < 4; ++r) {
            float denom = __shfl(oacc[m][4][r], (lane & 48));
            inv[r] = 1.0f / denom;
        }
#pragma unroll
        for (int n = 0; n < 4; ++n)
#pragma unroll
            for (int r = 0; r < 4; ++r) {
                int s = q0 + m * 16 + lg * 4 + r;
                int p = n * 16 + lr;
                Att[((size_t)b * 2048 + s) * 512 + h * 64 + p] =
                    f2bf(oacc[m][n][r] * inv[r]);
            }
    }
}

// ---------------------------------------------------------------------------
// Output projection: Out[8192][512] = Att[8192][512] * Wo  (single bf16)
// ---------------------------------------------------------------------------
__global__ __launch_bounds__(256) void outproj_kernel(
    const unsigned short* __restrict__ A,
    const unsigned short* __restrict__ WT,   // [512 col][512 k]
    float* __restrict__ Out)
{
    const int lane = threadIdx.x & 63;
    const int wave = threadIdx.x >> 6;
    const int lr = lane & 15, lg = lane >> 4;
    const int blk = blockIdx.x;
    const int xcd = blk & 7;
    const int loc = blk >> 3;
    const int rb = xcd * 16 + (loc >> 3);
    const int cb = loc & 7;
    const int row0 = rb * 64 + wave * 16;
    const int col0 = cb * 64;

    f32x4 acc[4];
#pragma unroll
    for (int n = 0; n < 4; ++n) acc[n] = {0.f, 0.f, 0.f, 0.f};

    for (int ks = 0; ks < 16; ++ks) {
        const int k0 = ks * 32 + lg * 8;
        bf16x8 af = *reinterpret_cast<const bf16x8*>(
            A + (size_t)(row0 + lr) * 512 + k0);
#pragma unroll
        for (int n = 0; n < 4; ++n) {
            bf16x8 bf = *reinterpret_cast<const bf16x8*>(
                WT + (size_t)(col0 + n * 16 + lr) * 512 + k0);
            acc[n] = MFMA(af, bf, acc[n], 0, 0, 0);
        }
    }

#pragma unroll
    for (int n = 0; n < 4; ++n)
#pragma unroll
        for (int r = 0; r < 4; ++r)
            Out[(size_t)(row0 + lg * 4 + r) * 512 + col0 + n * 16 + lr] =
                acc[n][r];
}

// ---------------------------------------------------------------------------
extern "C" void kernel_launch(void* const* d_in, const int* in_sizes, int n_in,
                              void* d_out, int out_size, void* d_ws, size_t ws_size,
                              hipStream_t stream) {
    (void)in_sizes; (void)n_in; (void)out_size; (void)ws_size;
    const float* q  = (const float*)d_in[0];
    const float* k  = (const float*)d_in[1];
    const float* v  = (const float*)d_in[2];
    const float* Wq = (const float*)d_in[3];
    const float* Wk = (const float*)d_in[4];
    const float* Wv = (const float*)d_in[5];
    const float* Wo = (const float*)d_in[6];
    float* out = (float*)d_out;

    size_t off = 0;
    auto take = [&](size_t bytes) -> void* {
        void* p = (char*)d_ws + off;
        off += (bytes + 255) & ~(size_t)255;
        return p;
    };
    const size_t WSZ  = 512 * 512 * sizeof(unsigned short);              // 512 KB
    const size_t BSZ  = (size_t)32 * 2048 * 64 * sizeof(unsigned short); // 8 MB
    const size_t VTSZ = (size_t)32 * 96 * 2048 * sizeof(unsigned short); // 12 MB

    unsigned short* WqTh = (unsigned short*)take(WSZ);
    unsigned short* WqTl = (unsigned short*)take(WSZ);
    unsigned short* WkTh = (unsigned short*)take(WSZ);
    unsigned short* WkTl = (unsigned short*)take(WSZ);
    unsigned short* WvTh = (unsigned short*)take(WSZ);
    unsigned short* WoT  = (unsigned short*)take(WSZ);
    unsigned short* Qh   = (unsigned short*)take(BSZ);
    unsigned short* Ql   = (unsigned short*)take(BSZ);
    unsigned short* Kh   = (unsigned short*)take(BSZ);
    unsigned short* Kl   = (unsigned short*)take(BSZ);
    unsigned short* VT   = (unsigned short*)take(VTSZ);
    unsigned short* Att  = (unsigned short*)take(BSZ);

    // weight prep (1/sqrt(P)=0.125 folded into Wq); Wv/Wo single bf16
    prep_w<<<1024, 256, 0, stream>>>(Wq, WqTh, WqTl, 0.125f, 1);
    prep_w<<<1024, 256, 0, stream>>>(Wk, WkTh, WkTl, 1.0f, 1);
    prep_w<<<1024, 256, 0, stream>>>(Wv, WvTh, nullptr, 1.0f, 1);
    prep_w<<<1024, 256, 0, stream>>>(Wo, WoT, nullptr, 1.0f, 0);
    vt_init<<<4096, 256, 0, stream>>>(VT);

    // projections (q,k: split 3-term; v: single-term)
    proj_kernel<<<1024, 256, 0, stream>>>(q, WqTh, WqTl, Qh, Ql, 0);
    proj_kernel<<<1024, 256, 0, stream>>>(k, WkTh, WkTl, Kh, Kl, 0);
    proj_kernel<<<1024, 256, 0, stream>>>(v, WvTh, nullptr, VT, nullptr, 1);

    // flash attention (512 blocks = 32 bh x 16 q-tiles)
    attn_kernel<<<512, 256, 0, stream>>>(Qh, Ql, Kh, Kl, VT, Att);

    // output projection
    outproj_kernel<<<1024, 256, 0, stream>>>(Att, WoT, out);
}